// Round 6
// baseline (37.022 us; speedup 1.0000x reference)
//
#include <hip/hip_runtime.h>

constexpr int B   = 1024;
constexpr int N   = 4096;
constexpr int BLK = 512;                 // 8 waves; one block per batch
constexpr int VPT = N / BLK;             // 8 lane-dense strided n's per thread
constexpr float C01 = 0.4082482904638630f;  // sqrt(0.5)/sqrt(3)
constexpr float C11 = 0.2886751345948129f;  // sqrt(0.5)/sqrt(6)

typedef float f32x4 __attribute__((ext_vector_type(4)));

// One block per batch: reduce tp_out over all N, then in-block MLP 3->128->3.
__global__ __launch_bounds__(BLK) void fused_kernel(
    const float* __restrict__ feats,      // (B, N, 8)
    const float* __restrict__ edge_attr,  // (B, N, 3)
    const float* __restrict__ w_path0,    // (5,)
    const float* __restrict__ w_path1,    // (1,)
    const float* __restrict__ W1,         // (3, 128)
    const float* __restrict__ b1,         // (128,)
    const float* __restrict__ W2,         // (128, 3)
    const float* __restrict__ b2,         // (3,)
    float* __restrict__ out)              // (B, 3)
{
    const int b = blockIdx.x;
    const int t = threadIdx.x;
    const long base = (long)b * N;

    const float w0 = w_path0[0], w1 = w_path0[1], w2 = w_path0[2],
                w3 = w_path0[3], w4 = w_path0[4];
    const float c11w = C11 * w_path1[0];

    float acc0 = 0.0f, acc1 = 0.0f, acc2 = 0.0f;

    #pragma unroll
    for (int k = 0; k < VPT; ++k) {
        const long idx = base + k * BLK + t;   // lane-dense per instruction

        const f32x4* fp = reinterpret_cast<const f32x4*>(feats + idx * 8);
        f32x4 f0 = __builtin_nontemporal_load(fp);
        f32x4 f1 = __builtin_nontemporal_load(fp + 1);

        const float* ep = edge_attr + idx * 3;
        float e0 = __builtin_nontemporal_load(ep);
        float e1 = __builtin_nontemporal_load(ep + 1);
        float e2 = __builtin_nontemporal_load(ep + 2);

        float s = f0.x * w0 + f0.y * w1 + f0.z * w2 + f0.w * w3 + f1.x * w4;
        float c01s = C01 * s;
        float v0 = f1.y, v1 = f1.z, v2 = f1.w;

        acc0 += c01s * e0 + c11w * (v1 * e2 - v2 * e1);
        acc1 += c01s * e1 + c11w * (v2 * e0 - v0 * e2);
        acc2 += c01s * e2 + c11w * (v0 * e1 - v1 * e0);
    }

    // per-wave shuffle reduce
    #pragma unroll
    for (int off = 32; off > 0; off >>= 1) {
        acc0 += __shfl_down(acc0, off);
        acc1 += __shfl_down(acc1, off);
        acc2 += __shfl_down(acc2, off);
    }

    __shared__ float wsum[8][3];
    const int wave = t >> 6;
    const int lane = t & 63;
    if (lane == 0) {
        wsum[wave][0] = acc0;
        wsum[wave][1] = acc1;
        wsum[wave][2] = acc2;
    }
    __syncthreads();

    __shared__ float g[3];
    if (t < 3) {
        float s = 0.0f;
        #pragma unroll
        for (int w = 0; w < 8; ++w) s += wsum[w][t];
        g[t] = s * (1.0f / (float)N);
    }
    __syncthreads();

    // MLP on waves 0 and 1: thread j (<128) owns hidden unit j.
    __shared__ float pr[2][3];
    if (t < 128) {
        float h = b1[t] + g[0] * W1[t] + g[1] * W1[128 + t] + g[2] * W1[256 + t];
        h = fmaxf(h, 0.0f);
        float p0 = h * W2[t * 3 + 0];
        float p1 = h * W2[t * 3 + 1];
        float p2 = h * W2[t * 3 + 2];
        #pragma unroll
        for (int off = 32; off > 0; off >>= 1) {
            p0 += __shfl_down(p0, off);
            p1 += __shfl_down(p1, off);
            p2 += __shfl_down(p2, off);
        }
        if (lane == 0) {
            pr[wave][0] = p0;
            pr[wave][1] = p1;
            pr[wave][2] = p2;
        }
    }
    __syncthreads();
    if (t < 3) {
        out[(long)b * 3 + t] = pr[0][t] + pr[1][t] + b2[t];
    }
}

extern "C" void kernel_launch(void* const* d_in, const int* in_sizes, int n_in,
                              void* d_out, int out_size, void* d_ws, size_t ws_size,
                              hipStream_t stream) {
    const float* feats     = (const float*)d_in[0];
    const float* edge_attr = (const float*)d_in[1];
    const float* w_path0   = (const float*)d_in[2];
    const float* w_path1   = (const float*)d_in[3];
    const float* W1        = (const float*)d_in[4];
    const float* b1        = (const float*)d_in[5];
    const float* W2        = (const float*)d_in[6];
    const float* b2        = (const float*)d_in[7];
    float* out = (float*)d_out;

    fused_kernel<<<B, BLK, 0, stream>>>(feats, edge_attr, w_path0, w_path1,
                                        W1, b1, W2, b2, out);
}

// Round 7
// 35.296 us; speedup vs baseline: 1.0489x; 1.0489x over previous
//
#include <hip/hip_runtime.h>

constexpr int B   = 1024;
constexpr int N   = 4096;
constexpr int BLK = 256;                 // 4 waves; one n per thread
constexpr int BLOCKS_PER_BATCH = N / BLK;            // 16
constexpr int WAVES_PER_BATCH  = BLOCKS_PER_BATCH * (BLK / 64);  // 64
constexpr float C01 = 0.4082482904638630f;  // sqrt(0.5)/sqrt(3)
constexpr float C11 = 0.2886751345948129f;  // sqrt(0.5)/sqrt(6)

typedef float f32x4 __attribute__((ext_vector_type(4)));
// 4-byte-aligned float4 for the 12B-strided edge loads
typedef float f32x4_a4 __attribute__((ext_vector_type(4), aligned(4)));

// Stage 1: grid = B*16 blocks x 256 threads, one n per thread.
// feats: 2x dense float4 NT. edge_attr: ONE dwordx4 per lane (12B stride,
// 4th component discarded) -- same cache-line footprint, 1/3 the VMEM ops.
__global__ __launch_bounds__(BLK) void tp_reduce_kernel(
    const float* __restrict__ feats,      // (B, N, 8)
    const float* __restrict__ edge_attr,  // (B, N, 3)
    const float* __restrict__ w_path0,    // (5,)
    const float* __restrict__ w_path1,    // (1,)
    float* __restrict__ part)             // (B*64, 3) per-wave partials
{
    const int blk = blockIdx.x;
    const int b   = blk >> 4;
    const int q   = blk & 15;
    const int t   = threadIdx.x;
    const long idx = (long)b * N + (q << 8) + t;

    const f32x4* fp = reinterpret_cast<const f32x4*>(feats + idx * 8);
    f32x4 f0 = __builtin_nontemporal_load(fp);
    f32x4 f1 = __builtin_nontemporal_load(fp + 1);

    float e0, e1, e2;
    if (blk != B * BLOCKS_PER_BATCH - 1) {
        // one 16B load per lane; last float discarded. In-bounds for all
        // blocks except the very last one.
        const f32x4_a4* ep = reinterpret_cast<const f32x4_a4*>(edge_attr + idx * 3);
        f32x4_a4 ev = __builtin_nontemporal_load(ep);
        e0 = ev.x; e1 = ev.y; e2 = ev.z;
    } else {
        const float* ep = edge_attr + idx * 3;
        e0 = ep[0]; e1 = ep[1]; e2 = ep[2];
    }

    const float s = f0.x * w_path0[0] + f0.y * w_path0[1] + f0.z * w_path0[2]
                  + f0.w * w_path0[3] + f1.x * w_path0[4];
    const float c01s = C01 * s;
    const float c11w = C11 * w_path1[0];
    const float v0 = f1.y, v1 = f1.z, v2 = f1.w;

    float t0 = c01s * e0 + c11w * (v1 * e2 - v2 * e1);
    float t1 = c01s * e1 + c11w * (v2 * e0 - v0 * e2);
    float t2 = c01s * e2 + c11w * (v0 * e1 - v1 * e0);

    #pragma unroll
    for (int off = 32; off > 0; off >>= 1) {
        t0 += __shfl_down(t0, off);
        t1 += __shfl_down(t1, off);
        t2 += __shfl_down(t2, off);
    }

    if ((t & 63) == 0) {
        const int w = (q << 2) + (t >> 6);   // wave index within batch, 0..63
        float* p = part + ((long)b * WAVES_PER_BATCH + w) * 3;
        p[0] = t0;
        p[1] = t1;
        p[2] = t2;
    }
}

// Stage 2: one wave per batch. Sum 64 partials, then MLP 3->128(relu)->3.
__global__ __launch_bounds__(64) void mlp_kernel(
    const float* __restrict__ part,  // (B*64, 3)
    const float* __restrict__ W1,    // (3, 128)
    const float* __restrict__ b1,    // (128,)
    const float* __restrict__ W2,    // (128, 3)
    const float* __restrict__ b2,    // (3,)
    float* __restrict__ out)         // (B, 3)
{
    const int b = blockIdx.x;
    const int l = threadIdx.x;  // 0..63

    const float* p = part + ((long)b * WAVES_PER_BATCH + l) * 3;
    float a0 = p[0], a1 = p[1], a2 = p[2];

    #pragma unroll
    for (int off = 32; off > 0; off >>= 1) {
        a0 += __shfl_down(a0, off);
        a1 += __shfl_down(a1, off);
        a2 += __shfl_down(a2, off);
    }
    const float g0 = __shfl(a0, 0) * (1.0f / (float)N);
    const float g1 = __shfl(a1, 0) * (1.0f / (float)N);
    const float g2 = __shfl(a2, 0) * (1.0f / (float)N);

    float p0 = 0.0f, p1 = 0.0f, p2 = 0.0f;
    #pragma unroll
    for (int half = 0; half < 2; ++half) {
        const int j = l + half * 64;
        float h = b1[j] + g0 * W1[j] + g1 * W1[128 + j] + g2 * W1[256 + j];
        h = fmaxf(h, 0.0f);
        p0 += h * W2[j * 3 + 0];
        p1 += h * W2[j * 3 + 1];
        p2 += h * W2[j * 3 + 2];
    }
    #pragma unroll
    for (int off = 32; off > 0; off >>= 1) {
        p0 += __shfl_down(p0, off);
        p1 += __shfl_down(p1, off);
        p2 += __shfl_down(p2, off);
    }
    if (l == 0) {
        float* o = out + (long)b * 3;
        o[0] = p0 + b2[0];
        o[1] = p1 + b2[1];
        o[2] = p2 + b2[2];
    }
}

extern "C" void kernel_launch(void* const* d_in, const int* in_sizes, int n_in,
                              void* d_out, int out_size, void* d_ws, size_t ws_size,
                              hipStream_t stream) {
    const float* feats     = (const float*)d_in[0];
    const float* edge_attr = (const float*)d_in[1];
    const float* w_path0   = (const float*)d_in[2];
    const float* w_path1   = (const float*)d_in[3];
    const float* W1        = (const float*)d_in[4];
    const float* b1        = (const float*)d_in[5];
    const float* W2        = (const float*)d_in[6];
    const float* b2        = (const float*)d_in[7];
    float* out = (float*)d_out;

    float* part = (float*)d_ws;  // B*64*3 floats = 768 KiB

    tp_reduce_kernel<<<B * BLOCKS_PER_BATCH, BLK, 0, stream>>>(
        feats, edge_attr, w_path0, w_path1, part);
    mlp_kernel<<<B, 64, 0, stream>>>(part, W1, b1, W2, b2, out);
}